// Round 7
// baseline (238.856 us; speedup 1.0000x reference)
//
#include <hip/hip_runtime.h>

// DistoLayer, fully reassociated:
//   WC[e, h*64+d'] = (1/8) * sum_d Wq[e,d] * Wk[d', h*64+d]      [64, 512]
//   A[m, c]        = sum_e x[dst[m], e] * WC[e, c]    (LDS only, per block)
//   pair[m,k,h]    = sum_d' x[src[m,k], d'] * A[m, h*64+d']
//   hidden = relu(pair @ Wp1); logits = hidden @ Wp2             [M*K, C]
//
// disto_AB v3: 625 blocks x 512 thr, block owns 16 m's.
//  - prologue: gather dst rows, A for all 16 m's -> LDS (wc col in 64 VGPR,
//    dead afterwards), ONE barrier.
//  - k-loop: BARRIER-FREE. wave (ml_w,ch) x 8 pairs; lane (h_role,k8) dots
//    x[src] row DIRECT FROM GLOBAL (8-lane broadcast, L1/L2-hot) against
//    a_all row from LDS (16 ds_read_b128, conflict-free). Wp1 row + Wp2
//    8x8 slice in registers (m-independent). DS insts/task: 50 -> 16.
//  __launch_bounds__(512,4): VGPR cap 128 (65..128 all cost 4 waves/SIMD).

#define Mm 10000
#define Kk 32
#define Dd 64
#define Hh 8
#define Cc 64

constexpr int MB_ = 16;
constexpr size_t WC_FLOATS = 64 * 512;
constexpr size_t WS_NEED = WC_FLOATS * sizeof(float);   // 128 KB

// ------------------------------------------------------------- wc_build
__global__ __launch_bounds__(256) void wc_build(
    const float* __restrict__ Wq,
    const float* __restrict__ Wk,
    float* __restrict__ WC)
{
    __shared__ float wq_l[16][68];
    __shared__ float wk_l[64][68];

    const int t  = threadIdx.x;
    const int e0 = blockIdx.x * 16;
    const int h  = blockIdx.y;

    {
        int r = t >> 4, q = t & 15;
        float4 v = ((const float4*)Wq)[(e0 + r) * 16 + q];
        *(float4*)&wq_l[r][q * 4] = v;
    }
    #pragma unroll
    for (int p = 0; p < 4; ++p) {
        int task = p * 256 + t;
        int dp = task >> 4, q = task & 15;
        float4 v = ((const float4*)Wk)[(size_t)dp * 128 + h * 16 + q];
        *(float4*)&wk_l[dp][q * 4] = v;
    }
    __syncthreads();

    const int dp = t & 63;
    const int eq = t >> 6;

    float4 wr[16];
    #pragma unroll
    for (int d4 = 0; d4 < 16; ++d4) wr[d4] = *(const float4*)&wk_l[dp][d4 * 4];

    #pragma unroll
    for (int i = 0; i < 4; ++i) {
        const int er = eq * 4 + i;
        float acc = 0.f;
        #pragma unroll
        for (int d4 = 0; d4 < 16; ++d4) {
            float4 qv = *(const float4*)&wq_l[er][d4 * 4];
            acc = fmaf(qv.x, wr[d4].x, acc);
            acc = fmaf(qv.y, wr[d4].y, acc);
            acc = fmaf(qv.z, wr[d4].z, acc);
            acc = fmaf(qv.w, wr[d4].w, acc);
        }
        WC[(size_t)(e0 + er) * 512 + h * 64 + dp] = acc * 0.125f;
    }
}

// ------------------------------------------------------------- disto_AB v3
__global__ __launch_bounds__(512, 4) void disto_AB(
    const float* __restrict__ x,
    const int*   __restrict__ src_idx,
    const int*   __restrict__ dst_idx,
    const float* __restrict__ WC,
    const float* __restrict__ Wp1,
    const float* __restrict__ Wp2,
    float* __restrict__ out)
{
    __shared__ float a_all[MB_][Hh][68];   // 34816 B, conflict-free row map
    __shared__ float dstx[MB_][68];        //  4352 B
    __shared__ int   idx_l[MB_ * Kk];      //  2048 B

    const int t  = threadIdx.x;
    const int m0 = blockIdx.x * MB_;

    // ---- prologue ----
    idx_l[t] = src_idx[m0 * Kk + t];                       // 512 = 16*32
    if (t < 256) {                                         // 16 dst rows
        int r = t >> 4, q = t & 15;
        float4 v = ((const float4*)x)[(size_t)dst_idx[m0 + r] * 16 + q];
        *(float4*)&dstx[r][q * 4] = v;
    }
    float wc[64];                                          // WC column t
    #pragma unroll
    for (int e = 0; e < 64; ++e) wc[e] = WC[(size_t)e * 512 + t];

    __syncthreads();

    // A for all 16 m's: thread t owns column c = t = hh*64+dp
    const int hh = t >> 6, dp = t & 63;
    for (int ml = 0; ml < MB_; ++ml) {
        float a0 = 0.f, a1 = 0.f;
        #pragma unroll
        for (int e4 = 0; e4 < 16; ++e4) {
            float4 xv = *(const float4*)&dstx[ml][e4 * 4];   // broadcast
            a0 = fmaf(xv.x, wc[e4 * 4 + 0], a0);
            a1 = fmaf(xv.y, wc[e4 * 4 + 1], a1);
            a0 = fmaf(xv.z, wc[e4 * 4 + 2], a0);
            a1 = fmaf(xv.w, wc[e4 * 4 + 3], a1);
        }
        a_all[ml][hh][dp] = a0 + a1;
    }
    __syncthreads();   // a_all ready; wc dead from here on

    // ---- k-loop roles ----
    const int w = t >> 6, l = t & 63;
    const int ml_w = w >> 2, ch = w & 3;     // wave -> (m parity, k-chunk)
    const int h_role = l & 7, k8 = l >> 3;

    float wp1r[8];                           // Wp1[h_role][*]
    #pragma unroll
    for (int j = 0; j < 8; ++j) wp1r[j] = Wp1[h_role * Hh + j];

    float wp2r[8][8];                        // Wp2[hp][h_role*8 + cc]
    #pragma unroll
    for (int hp = 0; hp < 8; ++hp) {
        float4 wa = ((const float4*)Wp2)[hp * 16 + h_role * 2];
        float4 wb = ((const float4*)Wp2)[hp * 16 + h_role * 2 + 1];
        wp2r[hp][0] = wa.x; wp2r[hp][1] = wa.y; wp2r[hp][2] = wa.z; wp2r[hp][3] = wa.w;
        wp2r[hp][4] = wb.x; wp2r[hp][5] = wb.y; wp2r[hp][6] = wb.z; wp2r[hp][7] = wb.w;
    }

    // ---- 8 independent tasks per wave, no barriers ----
    for (int p = 0; p < 8; ++p) {
        const int mloc = p * 2 + ml_w;
        const int ridx = idx_l[mloc * Kk + ch * 8 + k8];     // LDS b32, 8 distinct
        const float4* xr = (const float4*)(x + (size_t)ridx * Dd);  // global, bcast x8
        const float4* ar = (const float4*)a_all[mloc][h_role];      // LDS, conflict-free

        float p0 = 0.f, p1 = 0.f;
        #pragma unroll
        for (int d4 = 0; d4 < 16; d4 += 2) {
            float4 xv0 = xr[d4],     av0 = ar[d4];
            float4 xv1 = xr[d4 + 1], av1 = ar[d4 + 1];
            p0 = fmaf(xv0.x, av0.x, p0); p1 = fmaf(xv1.x, av1.x, p1);
            p0 = fmaf(xv0.y, av0.y, p0); p1 = fmaf(xv1.y, av1.y, p1);
            p0 = fmaf(xv0.z, av0.z, p0); p1 = fmaf(xv1.z, av1.z, p1);
            p0 = fmaf(xv0.w, av0.w, p0); p1 = fmaf(xv1.w, av1.w, p1);
        }
        const float pair = p0 + p1;

        // hid[j] = relu(sum_h pair_h * Wp1[h][j]) via h-octet butterfly
        float hid[8];
        #pragma unroll
        for (int j = 0; j < 8; ++j) hid[j] = pair * wp1r[j];
        #pragma unroll
        for (int s = 1; s < 8; s <<= 1) {
            #pragma unroll
            for (int j = 0; j < 8; ++j)
                hid[j] += __shfl_xor(hid[j], s, 64);
        }
        #pragma unroll
        for (int j = 0; j < 8; ++j) hid[j] = fmaxf(hid[j], 0.f);

        // logits cols [h_role*8, +8) from register-resident Wp2 slice
        float lg[8] = {0, 0, 0, 0, 0, 0, 0, 0};
        #pragma unroll
        for (int hp = 0; hp < 8; ++hp) {
            #pragma unroll
            for (int cc = 0; cc < 8; ++cc)
                lg[cc] = fmaf(hid[hp], wp2r[hp][cc], lg[cc]);
        }
        size_t row = (size_t)(m0 + mloc) * Kk + ch * 8 + k8;
        float4* o4 = (float4*)(out + row * Cc + h_role * 8);
        o4[0] = make_float4(lg[0], lg[1], lg[2], lg[3]);
        o4[1] = make_float4(lg[4], lg[5], lg[6], lg[7]);
    }
}

// ------------------------------------------------- fallback fused kernel
constexpr int WAVES = 4;
constexpr int PAD = 68;

__global__ __launch_bounds__(256) void disto_fused(
    const float* __restrict__ x,
    const int*   __restrict__ src_idx,
    const int*   __restrict__ dst_idx,
    const float* __restrict__ Wq,
    const float* __restrict__ Wk,
    const float* __restrict__ Wp1,
    const float* __restrict__ Wp2,
    float* __restrict__ out)
{
    __shared__ float ni_lds[WAVES][Dd];
    __shared__ float A_lds[WAVES][Hh][PAD];
    __shared__ float xs_lds[WAVES][8][PAD];
    __shared__ float wp2_lds[Hh * Cc];

    const int t = threadIdx.x;
    const int w = t >> 6;
    const int l = t & 63;
    const int m = blockIdx.x * WAVES + w;

    if (t < 128) ((float4*)wp2_lds)[t] = ((const float4*)Wp2)[t];

    const int dst = dst_idx[m];
    float xd = x[(size_t)dst * Dd + l];
    float acc1 = 0.f;
    #pragma unroll
    for (int dp = 0; dp < Dd; ++dp) {
        float xv = __shfl(xd, dp, 64);
        acc1 = fmaf(xv, Wq[dp * Dd + l], acc1);
    }
    ni_lds[w][l] = acc1;
    __syncthreads();
    {
        const float4* ni4 = (const float4*)ni_lds[w];
        const float4* wkrow = (const float4*)(Wk + (size_t)l * (Dd * Hh));
        #pragma unroll
        for (int h = 0; h < Hh; ++h) {
            float a = 0.f;
            #pragma unroll
            for (int d4 = 0; d4 < Dd / 4; ++d4) {
                float4 nv = ni4[d4];
                float4 wv = wkrow[h * (Dd / 4) + d4];
                a = fmaf(nv.x, wv.x, a);
                a = fmaf(nv.y, wv.y, a);
                a = fmaf(nv.z, wv.z, a);
                a = fmaf(nv.w, wv.w, a);
            }
            A_lds[w][h][l] = a * 0.125f;
        }
    }
    const int h_role = l & 7;
    const int k8 = l >> 3;
    float wp1r[8];
    #pragma unroll
    for (int j = 0; j < 8; ++j) wp1r[j] = Wp1[h_role * Hh + j];
    __syncthreads();

    for (int kc = 0; kc < 4; ++kc) {
        #pragma unroll
        for (int p = 0; p < 2; ++p) {
            int task = p * 64 + l;
            int r = task >> 4;
            int jq = task & 15;
            int idx = src_idx[m * Kk + kc * 8 + r];
            float4 v = ((const float4*)x)[(size_t)idx * (Dd / 4) + jq];
            *(float4*)&xs_lds[w][r][jq * 4] = v;
        }
        __syncthreads();
        float pair = 0.f;
        {
            const float4* xsr = (const float4*)xs_lds[w][k8];
            const float4* ar  = (const float4*)A_lds[w][h_role];
            #pragma unroll
            for (int d4 = 0; d4 < Dd / 4; ++d4) {
                float4 xv = xsr[d4];
                float4 av = ar[d4];
                pair = fmaf(xv.x, av.x, pair);
                pair = fmaf(xv.y, av.y, pair);
                pair = fmaf(xv.z, av.z, pair);
                pair = fmaf(xv.w, av.w, pair);
            }
        }
        float hid[8];
        #pragma unroll
        for (int j = 0; j < 8; ++j) hid[j] = pair * wp1r[j];
        #pragma unroll
        for (int s = 1; s < 8; s <<= 1) {
            #pragma unroll
            for (int j = 0; j < 8; ++j)
                hid[j] += __shfl_xor(hid[j], s, 64);
        }
        #pragma unroll
        for (int j = 0; j < 8; ++j) hid[j] = fmaxf(hid[j], 0.f);
        float lg[8] = {0,0,0,0,0,0,0,0};
        #pragma unroll
        for (int hp = 0; hp < 8; ++hp) {
            const float* wrow = &wp2_lds[hp * Cc + h_role * 8];
            float4 wa = *(const float4*)wrow;
            float4 wb = *(const float4*)(wrow + 4);
            lg[0] = fmaf(hid[hp], wa.x, lg[0]);
            lg[1] = fmaf(hid[hp], wa.y, lg[1]);
            lg[2] = fmaf(hid[hp], wa.z, lg[2]);
            lg[3] = fmaf(hid[hp], wa.w, lg[3]);
            lg[4] = fmaf(hid[hp], wb.x, lg[4]);
            lg[5] = fmaf(hid[hp], wb.y, lg[5]);
            lg[6] = fmaf(hid[hp], wb.z, lg[6]);
            lg[7] = fmaf(hid[hp], wb.w, lg[7]);
        }
        size_t row = (size_t)(m * Kk + kc * 8 + k8);
        float4* o4 = (float4*)(out + row * Cc + h_role * 8);
        o4[0] = make_float4(lg[0], lg[1], lg[2], lg[3]);
        o4[1] = make_float4(lg[4], lg[5], lg[6], lg[7]);
        __syncthreads();
    }
}

extern "C" void kernel_launch(void* const* d_in, const int* in_sizes, int n_in,
                              void* d_out, int out_size, void* d_ws, size_t ws_size,
                              hipStream_t stream) {
    const float* x       = (const float*)d_in[0];
    const int*   src_idx = (const int*)  d_in[1];
    const int*   dst_idx = (const int*)  d_in[2];
    const float* Wq      = (const float*)d_in[3];
    const float* Wk      = (const float*)d_in[4];
    const float* Wp1     = (const float*)d_in[5];
    const float* Wp2     = (const float*)d_in[6];
    float* out = (float*)d_out;

    if (ws_size >= WS_NEED) {
        float* WC = (float*)d_ws;
        wc_build<<<dim3(4, 8), dim3(256), 0, stream>>>(Wq, Wk, WC);
        disto_AB<<<dim3(Mm / MB_), dim3(512), 0, stream>>>(
            x, src_idx, dst_idx, WC, Wp1, Wp2, out);
    } else {
        disto_fused<<<dim3(Mm / WAVES), dim3(256), 0, stream>>>(
            x, src_idx, dst_idx, Wq, Wk, Wp1, Wp2, out);
    }
}